// Round 1
// baseline (156.991 us; speedup 1.0000x reference)
//
#include <hip/hip_runtime.h>
#include <math.h>

#define M_WAVE 32
#define NLEN 8192
#define FFT_N 16384
#define THREADS 512

__device__ __forceinline__ float2 cmulf(float2 a, float2 b) {
    return make_float2(a.x * b.x - a.y * b.y, a.x * b.y + a.y * b.x);
}

__device__ __forceinline__ float waveReduceMax(float v) {
    #pragma unroll
    for (int off = 32; off > 0; off >>= 1) v = fmaxf(v, __shfl_down(v, off, 64));
    return v;
}
__device__ __forceinline__ float waveReduceSum(float v) {
    #pragma unroll
    for (int off = 32; off > 0; off >>= 1) v += __shfl_down(v, off, 64);
    return v;
}

// Kernel 1: forward 16384-pt FFT per waveform (radix-2 DIF, natural in -> bit-reversed out)
__global__ __launch_bounds__(THREADS) void fwd_fft_kernel(const float* __restrict__ x,
                                                          float2* __restrict__ spec) {
    __shared__ float2 X[FFT_N];  // 128 KiB
    const int m = blockIdx.x;
    const int tid = threadIdx.x;
    const float TWOPI = 6.28318530717958647f;

    for (int i = tid; i < NLEN; i += THREADS) {
        float ph = TWOPI * x[m * NLEN + i];
        float s, c;
        __sincosf(ph, &s, &c);
        X[i] = make_float2(c, s);
        X[i + NLEN] = make_float2(0.f, 0.f);
    }
    __syncthreads();

    for (int lh = 13; lh >= 0; --lh) {          // mh = half-span
        const int mh = 1 << lh;
        const float angf = -3.14159265358979323846f / (float)mh;  // -pi*j/mh = -2pi*j/mlen
        for (int k = tid; k < (FFT_N >> 1); k += THREADS) {
            const int j = k & (mh - 1);
            const int i0 = ((k >> lh) << (lh + 1)) + j;
            const int i1 = i0 + mh;
            float2 u = X[i0], v = X[i1];
            float2 sum = make_float2(u.x + v.x, u.y + v.y);
            float2 dif = make_float2(u.x - v.x, u.y - v.y);
            float s, c;
            __sincosf(angf * (float)j, &s, &c);
            X[i0] = sum;
            X[i1] = make_float2(dif.x * c - dif.y * s, dif.x * s + dif.y * c);
        }
        __syncthreads();
    }

    for (int i = tid; i < FFT_N; i += THREADS) {
        spec[(size_t)m * FFT_N + i] = X[i];
    }
}

// Kernel 2: per ordered pair r=(a,b): P = spec[b]*conj(spec[a]) (bit-rev domain),
// inverse DIT (bitrev in -> natural out), then block reductions over used lags.
__global__ __launch_bounds__(THREADS) void pair_kernel(const float2* __restrict__ spec,
                                                       float4* __restrict__ rec) {
    __shared__ float2 X[FFT_N];  // 128 KiB
    const int r = blockIdx.x;
    const int a = r >> 5;
    const int b = r & 31;
    const int tid = threadIdx.x;
    const bool is_auto = (a == b);

    const float2* __restrict__ sa = spec + (size_t)a * FFT_N;
    const float2* __restrict__ sb = spec + (size_t)b * FFT_N;
    for (int k = tid; k < FFT_N; k += THREADS) {
        float2 A = sa[k], B = sb[k];
        // B * conj(A)
        X[k] = make_float2(B.x * A.x + B.y * A.y, B.y * A.x - B.x * A.y);
    }
    __syncthreads();

    for (int lh = 0; lh <= 13; ++lh) {
        const int mh = 1 << lh;
        const float angf = 3.14159265358979323846f / (float)mh;  // +pi*j/mh
        for (int k = tid; k < (FFT_N >> 1); k += THREADS) {
            const int j = k & (mh - 1);
            const int i0 = ((k >> lh) << (lh + 1)) + j;
            const int i1 = i0 + mh;
            float s, c;
            __sincosf(angf * (float)j, &s, &c);
            float2 u = X[i0];
            float2 w = X[i1];
            float2 v = make_float2(w.x * c - w.y * s, w.x * s + w.y * c);
            X[i0] = make_float2(u.x + v.x, u.y + v.y);
            X[i1] = make_float2(u.x - v.x, u.y - v.y);
        }
        __syncthreads();
    }

    // Used lags: i in [0,8192): t = (i==0) ? 0 : NLEN + i. Auto pairs exclude i==0.
    // u = 0.1 * |sigma|^2 where sigma = X / FFT_N (undivided-by-N^2 units, matching APSL/CPSL).
    const float CSCALE = 0.1f / ((float)FFT_N * (float)FFT_N);
    float uvals[16];
    float local_max = -1.0f;
    float local_sum = 0.0f;
    #pragma unroll
    for (int ii = 0; ii < 16; ++ii) {
        const int i = tid + ii * THREADS;
        const int t = (i == 0) ? 0 : (NLEN + i);
        float2 v = X[t];
        float u = CSCALE * (v.x * v.x + v.y * v.y);
        uvals[ii] = u;
        const bool valid = !(is_auto && i == 0);
        if (valid) {
            local_max = fmaxf(local_max, u);
            local_sum += u;
        }
    }
    __syncthreads();  // done reading X; reuse as reduction scratch

    float* scratch = (float*)X;
    const int wid = tid >> 6, lane = tid & 63;

    float wmax = waveReduceMax(local_max);
    float wsum = waveReduceSum(local_sum);
    if (lane == 0) { scratch[wid] = wmax; scratch[8 + wid] = wsum; }
    __syncthreads();
    float m_b = scratch[0];
    float sumu = scratch[8];
    #pragma unroll
    for (int i = 1; i < 8; ++i) {
        m_b = fmaxf(m_b, scratch[i]);
        sumu += scratch[8 + i];
    }

    // logsumexp partial: s_b = sum exp((u - m_b) / (T*N*N)), T*N*N = 67108.864
    const float invTN2 = 1.0f / 67108.864f;
    float ls = 0.0f;
    #pragma unroll
    for (int ii = 0; ii < 16; ++ii) {
        const bool valid = !(is_auto && tid == 0 && ii == 0);
        if (valid) ls += __expf((uvals[ii] - m_b) * invTN2);
    }
    float wls = waveReduceSum(ls);
    __syncthreads();
    if (lane == 0) scratch[16 + wid] = wls;
    __syncthreads();
    if (tid == 0) {
        float s_b = 0.0f;
        #pragma unroll
        for (int i = 0; i < 8; ++i) s_b += scratch[16 + i];
        rec[r] = make_float4(m_b, sumu, s_b, 0.0f);
    }
}

// Kernel 3: merge 1024 records -> 7 outputs.
__global__ __launch_bounds__(256) void final_kernel(const float4* __restrict__ rec,
                                                    float* __restrict__ out) {
    __shared__ float smaxA[256], smaxC[256];
    __shared__ double sS[256], sA[256], sC[256];
    const int tid = threadIdx.x;

    float maxA = -1.0f, maxC = -1.0f;
    for (int r = tid; r < 1024; r += 256) {
        float4 rv = rec[r];
        if (r % 33 == 0) maxA = fmaxf(maxA, rv.x);
        else             maxC = fmaxf(maxC, rv.x);
    }
    smaxA[tid] = maxA;
    smaxC[tid] = maxC;
    __syncthreads();
    for (int s = 128; s > 0; s >>= 1) {
        if (tid < s) {
            smaxA[tid] = fmaxf(smaxA[tid], smaxA[tid + s]);
            smaxC[tid] = fmaxf(smaxC[tid], smaxC[tid + s]);
        }
        __syncthreads();
    }
    const float maxA_g = smaxA[0];
    const float maxC_g = smaxC[0];
    const float Mall = fmaxf(maxA_g, maxC_g);

    const double invTN2 = 1.0 / 67108.864;  // 1/(T*N*N)
    double S = 0.0, sumA = 0.0, sumC = 0.0;
    for (int r = tid; r < 1024; r += 256) {
        float4 rv = rec[r];
        S += (double)rv.z * exp(((double)rv.x - (double)Mall) * invTN2);
        if (r % 33 == 0) sumA += (double)rv.y;
        else             sumC += (double)rv.y;
    }
    sS[tid] = S; sA[tid] = sumA; sC[tid] = sumC;
    __syncthreads();
    for (int s = 128; s > 0; s >>= 1) {
        if (tid < s) {
            sS[tid] += sS[tid + s];
            sA[tid] += sA[tid + s];
            sC[tid] += sC[tid + s];
        }
        __syncthreads();
    }

    if (tid == 0) {
        const double invN2 = 1.0 / 67108864.0;  // 1/N^2
        const double Sall = sS[0];
        const double At = sA[0], Ct = sC[0];
        out[0] = (float)((double)Mall * invN2 + 1e-3 * log(Sall));  // loss
        out[1] = (float)((double)Mall * invN2);                     // PSL
        out[2] = maxA_g;                                            // APSL
        out[3] = maxC_g;                                            // CPSL
        out[4] = (float)((At + Ct) * invN2);                        // ISL
        out[5] = (float)At;                                         // AISL
        out[6] = (float)Ct;                                         // CISL
    }
}

extern "C" void kernel_launch(void* const* d_in, const int* in_sizes, int n_in,
                              void* d_out, int out_size, void* d_ws, size_t ws_size,
                              hipStream_t stream) {
    (void)in_sizes; (void)n_in; (void)out_size; (void)ws_size;
    const float* x = (const float*)d_in[0];
    float* out = (float*)d_out;

    float2* spec = (float2*)d_ws;
    float4* rec = (float4*)((char*)d_ws + (size_t)M_WAVE * FFT_N * sizeof(float2));

    fwd_fft_kernel<<<M_WAVE, THREADS, 0, stream>>>(x, spec);
    pair_kernel<<<M_WAVE * M_WAVE, THREADS, 0, stream>>>(spec, rec);
    final_kernel<<<1, 256, 0, stream>>>(rec, out);
}

// Round 2
// 84.115 us; speedup vs baseline: 1.8664x; 1.8664x over previous
//
#include <hip/hip_runtime.h>
#include <math.h>

#define M_WAVE 32
#define NLEN 8192
#define FFT_N 16384
#define THREADS 1024
#define NPAIR 528   // 32 autos + 496 unordered cross pairs

#define TWOPI_F 6.28318530717958647692f
#define PI_F    3.14159265358979323846f

__device__ __forceinline__ float2 cadd(float2 a, float2 b){return make_float2(a.x+b.x, a.y+b.y);}
__device__ __forceinline__ float2 csub(float2 a, float2 b){return make_float2(a.x-b.x, a.y-b.y);}
__device__ __forceinline__ float2 cmul(float2 a, float2 b){return make_float2(a.x*b.x-a.y*b.y, a.x*b.y+a.y*b.x);}
__device__ __forceinline__ float2 mul_i (float2 a){return make_float2(-a.y,  a.x);}   //  i*a
__device__ __forceinline__ float2 mul_mi(float2 a){return make_float2( a.y, -a.x);}   // -i*a
__device__ __forceinline__ float2 shflx2(float2 v, int m){
    return make_float2(__shfl_xor(v.x, m, 64), __shfl_xor(v.y, m, 64));
}

__device__ __forceinline__ float waveReduceMax(float v) {
    #pragma unroll
    for (int off = 32; off > 0; off >>= 1) v = fmaxf(v, __shfl_down(v, off, 64));
    return v;
}
__device__ __forceinline__ float waveReduceSum(float v) {
    #pragma unroll
    for (int off = 32; off > 0; off >>= 1) v += __shfl_down(v, off, 64);
    return v;
}

// ---- radix-4 DIF forward stage (LDS, in-place). L = span, q = L/4 >= 64 -> conflict-free.
template<int L>
__device__ __forceinline__ void fwd_r4_stage(float2* X, int tid){
    constexpr int q = L/4;
    const float ang = -TWOPI_F/(float)L;
    #pragma unroll
    for (int ii = 0; ii < 4; ++ii){
        int k = tid + (ii<<10);
        int j = k & (q-1);
        int base = ((k & ~(q-1))<<2) + j;
        float2 a=X[base], b=X[base+q], c=X[base+2*q], d=X[base+3*q];
        float2 t0=cadd(a,c), t1=csub(a,c), t2=cadd(b,d), t3=csub(b,d);
        float2 mit3 = mul_mi(t3);
        float2 u0=cadd(t0,t2), u2=csub(t0,t2);
        float2 u1=cadd(t1,mit3), u3=csub(t1,mit3);
        float s,cw; __sincosf(ang*(float)j,&s,&cw);
        float2 w1=make_float2(cw,s), w2=cmul(w1,w1), w3=cmul(w2,w1);
        X[base]=u0; X[base+q]=cmul(u1,w1); X[base+2*q]=cmul(u2,w2); X[base+3*q]=cmul(u3,w3);
    }
}

// ---- radix-4 DIT inverse stage (LDS, in-place), transpose-conjugate of fwd_r4_stage.
template<int L>
__device__ __forceinline__ void inv_r4_stage(float2* X, int tid){
    constexpr int q = L/4;
    const float ang = TWOPI_F/(float)L;
    #pragma unroll
    for (int ii = 0; ii < 4; ++ii){
        int k = tid + (ii<<10);
        int j = k & (q-1);
        int base = ((k & ~(q-1))<<2) + j;
        float2 v0=X[base], v1=X[base+q], v2=X[base+2*q], v3=X[base+3*q];
        float s,cw; __sincosf(ang*(float)j,&s,&cw);
        float2 w1=make_float2(cw,s), w2=cmul(w1,w1), w3=cmul(w2,w1);
        v1=cmul(v1,w1); v2=cmul(v2,w2); v3=cmul(v3,w3);
        float2 t0=cadd(v0,v2), t1=csub(v0,v2), t2=cadd(v1,v3), t3=csub(v1,v3);
        float2 it3 = mul_i(t3);
        X[base]       = cadd(t0,t2);
        X[base+q]     = cadd(t1,it3);
        X[base+2*q]   = csub(t0,t2);
        X[base+3*q]   = csub(t1,it3);
    }
}

// Kernel 1: forward FFT per waveform. R4-DIF stage1 fused with exp(i*2pi*x) generation
// (zero-pad elided), 3 more R4 LDS stages, then 6 radix-2 DIF shfl stages within
// 64-element blocks. Output digit-reversed (consumers don't care about order).
__global__ __launch_bounds__(THREADS) void fwd_fft_kernel(const float* __restrict__ x,
                                                          float2* __restrict__ spec) {
    __shared__ float2 X[FFT_N];  // 128 KiB
    const int m = blockIdx.x;
    const int tid = threadIdx.x;

    // stage L=16384 fused: inputs (a,b,0,0)
    const float ang1 = -TWOPI_F/16384.0f;
    #pragma unroll
    for (int ii = 0; ii < 4; ++ii){
        int j = tid + (ii<<10);                      // 0..4095
        float xa = x[m*NLEN + j];
        float xb = x[m*NLEN + j + 4096];
        float sa,ca,sb,cb;
        __sincosf(TWOPI_F*xa,&sa,&ca);
        __sincosf(TWOPI_F*xb,&sb,&cb);
        float2 a=make_float2(ca,sa), b=make_float2(cb,sb);
        float2 u0=cadd(a,b), u2=csub(a,b);
        float2 u1=make_float2(a.x+b.y, a.y-b.x);     // a - i b
        float2 u3=make_float2(a.x-b.y, a.y+b.x);     // a + i b
        float s,cw; __sincosf(ang1*(float)j,&s,&cw);
        float2 w1=make_float2(cw,s), w2=cmul(w1,w1), w3=cmul(w2,w1);
        X[j]=u0; X[j+4096]=cmul(u1,w1); X[j+8192]=cmul(u2,w2); X[j+12288]=cmul(u3,w3);
    }
    __syncthreads();
    fwd_r4_stage<4096>(X, tid); __syncthreads();
    fwd_r4_stage<1024>(X, tid); __syncthreads();
    fwd_r4_stage<256>(X, tid);  __syncthreads();

    const int lane = tid & 63, wv = tid >> 6;        // 16 waves
    #pragma unroll 1
    for (int it = 0; it < 16; ++it){
        int blk = wv*16 + it;
        float2 v = X[blk*64 + lane];
        #pragma unroll
        for (int hb = 5; hb >= 0; --hb){
            int h = 1 << hb;
            float2 p = shflx2(v, h);
            bool bot = (lane & h) != 0;
            float jf = (float)(lane & (h-1));
            float s,c; __sincosf((-PI_F/(float)h)*jf, &s, &c);
            float2 sum = cadd(v, p);                 // top: a+b
            float2 dif = csub(p, v);                 // bottom: a-b (p=a, v=b)
            float2 tw  = cmul(dif, make_float2(c,s));
            v = bot ? tw : sum;
        }
        spec[(size_t)m*FFT_N + blk*64 + lane] = v;
    }
}

// Kernel 2: one block per unordered pair r -> (a<=b). P = spec[b]*conj(spec[a]) in
// digit-rev domain; inverse = transpose network: 6 R2-DIT shfl stages, 3 R4-DIT LDS
// stages, final L=16384 stage fused with magnitude + reductions (natural-order lags).
// Cross block covers BOTH ordered pairs: lags 1..N-1 belong to (b,a), N+1..2N-1 to
// (a,b), lag 0 to both (double-counted in sums), lag N unused. Autos: lags > N only.
__global__ __launch_bounds__(THREADS) void pair_kernel(const float2* __restrict__ spec,
                                                       float4* __restrict__ rec) {
    __shared__ float2 X[FFT_N];  // 128 KiB
    const int r = blockIdx.x;
    const int tid = threadIdx.x;
    int a, b;
    if (r < M_WAVE) { a = r; b = r; }
    else {
        int t = r - M_WAVE;
        a = 0; int rem = M_WAVE - 1;
        while (t >= rem) { t -= rem; ++a; rem = M_WAVE - 1 - a; }
        b = a + 1 + t;
    }
    const bool is_auto = (r < M_WAVE);
    const float2* __restrict__ sa = spec + (size_t)a * FFT_N;
    const float2* __restrict__ sb = spec + (size_t)b * FFT_N;

    const int lane = tid & 63, wv = tid >> 6;
    #pragma unroll 1
    for (int it = 0; it < 16; ++it){
        int idx = (wv*16 + it)*64 + lane;
        float2 A = sa[idx], B = sb[idx];
        float2 v = make_float2(B.x*A.x + B.y*A.y, B.y*A.x - B.x*A.y);  // B*conj(A)
        #pragma unroll
        for (int hb = 0; hb <= 5; ++hb){
            int h = 1 << hb;
            float2 p = shflx2(v, h);
            bool bot = (lane & h) != 0;
            float jf = (float)(lane & (h-1));
            float s,c; __sincosf((PI_F/(float)h)*jf, &s, &c);
            float2 bv = bot ? v : p;                 // b-input
            float2 av = bot ? p : v;                 // a-input
            float2 tw = cmul(bv, make_float2(c,s));
            v = bot ? csub(av, tw) : cadd(av, tw);
        }
        X[idx] = v;
    }
    __syncthreads();
    inv_r4_stage<256>(X, tid);  __syncthreads();
    inv_r4_stage<1024>(X, tid); __syncthreads();
    inv_r4_stage<4096>(X, tid); __syncthreads();

    // final stage L=16384 (q=4096, g=0) fused with stats; outputs natural lags
    // y_s at lag j + 4096*s.
    const float CSCALE = 0.1f / ((float)FFT_N * (float)FFT_N);
    const float angI = TWOPI_F/16384.0f;
    float uval[16];
    float lm = 0.f, lsum = 0.f;
    #pragma unroll
    for (int ii = 0; ii < 4; ++ii){
        int j = tid + (ii<<10);
        float2 v0=X[j], v1=X[j+4096], v2=X[j+8192], v3=X[j+12288];
        float s,cw; __sincosf(angI*(float)j,&s,&cw);
        float2 w1=make_float2(cw,s), w2=cmul(w1,w1), w3=cmul(w2,w1);
        v1=cmul(v1,w1); v2=cmul(v2,w2); v3=cmul(v3,w3);
        float2 t0=cadd(v0,v2), t1=csub(v0,v2), t2=cadd(v1,v3), t3=csub(v1,v3);
        float2 it3 = mul_i(t3);
        float2 y0=cadd(t0,t2), y1=cadd(t1,it3), y2=csub(t0,t2), y3=csub(t1,it3);
        float u0=CSCALE*(y0.x*y0.x+y0.y*y0.y);
        float u1=CSCALE*(y1.x*y1.x+y1.y*y1.y);
        float u2=CSCALE*(y2.x*y2.x+y2.y*y2.y);
        float u3=CSCALE*(y3.x*y3.x+y3.y*y3.y);
        uval[ii*4+0]=u0; uval[ii*4+1]=u1; uval[ii*4+2]=u2; uval[ii*4+3]=u3;
        if (is_auto){
            if (j > 0){ lm = fmaxf(lm,u2); lsum += u2; }
            lm = fmaxf(lm,u3); lsum += u3;
        } else {
            lm = fmaxf(fmaxf(lm,u0), fmaxf(u1,u3));
            if (j != 0){ lm = fmaxf(lm,u2); lsum += u0 + u1 + u2 + u3; }
            else       { lsum += 2.f*u0 + u1 + u3; }
        }
    }
    __syncthreads();  // all reads of X done; reuse as scratch

    float* scratch = (float*)X;
    float wm = waveReduceMax(lm);
    float wsm = waveReduceSum(lsum);
    if (lane == 0){ scratch[wv] = wm; scratch[16+wv] = wsm; }
    __syncthreads();
    float m_b = scratch[0], sumu = scratch[16];
    #pragma unroll
    for (int i = 1; i < 16; ++i){ m_b = fmaxf(m_b, scratch[i]); sumu += scratch[16+i]; }

    const float invTN2 = 1.0f/67108.864f;   // 1/(T*N*N)
    float le = 0.f;
    #pragma unroll
    for (int ii = 0; ii < 4; ++ii){
        int j = tid + (ii<<10);
        if (is_auto){
            if (j > 0) le += __expf((uval[ii*4+2]-m_b)*invTN2);
            le += __expf((uval[ii*4+3]-m_b)*invTN2);
        } else {
            float w0 = (j==0) ? 2.f : 1.f;
            le += w0*__expf((uval[ii*4+0]-m_b)*invTN2);
            le += __expf((uval[ii*4+1]-m_b)*invTN2);
            if (j != 0) le += __expf((uval[ii*4+2]-m_b)*invTN2);
            le += __expf((uval[ii*4+3]-m_b)*invTN2);
        }
    }
    float wle = waveReduceSum(le);
    if (lane == 0) scratch[32+wv] = wle;
    __syncthreads();
    if (tid == 0){
        float sb2 = 0.f;
        #pragma unroll
        for (int i = 0; i < 16; ++i) sb2 += scratch[32+i];
        rec[r] = make_float4(m_b, sumu, sb2, 0.f);
    }
}

// Kernel 3: merge 528 records -> 7 outputs.
__global__ __launch_bounds__(256) void final_kernel(const float4* __restrict__ rec,
                                                    float* __restrict__ out) {
    __shared__ float smA[256], smC[256];
    __shared__ double sS[256], sA[256], sC[256];
    const int tid = threadIdx.x;

    float mA = 0.f, mC = 0.f;
    for (int r = tid; r < NPAIR; r += 256){
        float mx = rec[r].x;
        if (r < M_WAVE) mA = fmaxf(mA, mx); else mC = fmaxf(mC, mx);
    }
    smA[tid] = mA; smC[tid] = mC;
    __syncthreads();
    for (int s = 128; s > 0; s >>= 1){
        if (tid < s){ smA[tid]=fmaxf(smA[tid],smA[tid+s]); smC[tid]=fmaxf(smC[tid],smC[tid+s]); }
        __syncthreads();
    }
    const float maxA_g = smA[0], maxC_g = smC[0];
    const float Mall = fmaxf(maxA_g, maxC_g);

    const double invTN2 = 1.0/67108.864;
    double S = 0.0, sumA = 0.0, sumC = 0.0;
    for (int r = tid; r < NPAIR; r += 256){
        float4 rv = rec[r];
        S += (double)rv.z * exp(((double)rv.x - (double)Mall)*invTN2);
        if (r < M_WAVE) sumA += (double)rv.y; else sumC += (double)rv.y;
    }
    sS[tid]=S; sA[tid]=sumA; sC[tid]=sumC;
    __syncthreads();
    for (int s = 128; s > 0; s >>= 1){
        if (tid < s){ sS[tid]+=sS[tid+s]; sA[tid]+=sA[tid+s]; sC[tid]+=sC[tid+s]; }
        __syncthreads();
    }
    if (tid == 0){
        const double invN2 = 1.0/67108864.0;
        out[0] = (float)((double)Mall*invN2 + 1e-3*log(sS[0]));
        out[1] = (float)((double)Mall*invN2);
        out[2] = maxA_g;
        out[3] = maxC_g;
        out[4] = (float)((sA[0]+sC[0])*invN2);
        out[5] = (float)sA[0];
        out[6] = (float)sC[0];
    }
}

extern "C" void kernel_launch(void* const* d_in, const int* in_sizes, int n_in,
                              void* d_out, int out_size, void* d_ws, size_t ws_size,
                              hipStream_t stream) {
    (void)in_sizes; (void)n_in; (void)out_size; (void)ws_size;
    const float* x = (const float*)d_in[0];
    float* out = (float*)d_out;

    float2* spec = (float2*)d_ws;
    float4* rec = (float4*)((char*)d_ws + (size_t)M_WAVE * FFT_N * sizeof(float2));

    fwd_fft_kernel<<<M_WAVE, THREADS, 0, stream>>>(x, spec);
    pair_kernel<<<NPAIR, THREADS, 0, stream>>>(spec, rec);
    final_kernel<<<1, 256, 0, stream>>>(rec, out);
}

// Round 3
// 70.656 us; speedup vs baseline: 2.2219x; 1.1905x over previous
//
#include <hip/hip_runtime.h>
#include <math.h>

#define M_WAVE 32
#define NLEN 8192
#define FFT_N 16384
#define THREADS 1024
#define NPAIR 528   // 32 autos + 496 unordered cross pairs

#define TWOPI_F 6.28318530717958647692f

__device__ __forceinline__ float2 cadd(float2 a, float2 b){return make_float2(a.x+b.x, a.y+b.y);}
__device__ __forceinline__ float2 csub(float2 a, float2 b){return make_float2(a.x-b.x, a.y-b.y);}
__device__ __forceinline__ float2 cmul(float2 a, float2 b){return make_float2(a.x*b.x-a.y*b.y, a.x*b.y+a.y*b.x);}
__device__ __forceinline__ float2 mul_i (float2 a){return make_float2(-a.y,  a.x);}   //  i*a
__device__ __forceinline__ float2 mul_mi(float2 a){return make_float2( a.y, -a.x);}   // -i*a

// DPP quad-perm exchanges within 4-lane groups (VALU pipe, no LDS traffic).
__device__ __forceinline__ float2 dpp_xor1(float2 v){
    float2 r;
    r.x = __int_as_float(__builtin_amdgcn_mov_dpp(__float_as_int(v.x), 0xB1, 0xF, 0xF, true));
    r.y = __int_as_float(__builtin_amdgcn_mov_dpp(__float_as_int(v.y), 0xB1, 0xF, 0xF, true));
    return r;
}
__device__ __forceinline__ float2 dpp_xor2(float2 v){
    float2 r;
    r.x = __int_as_float(__builtin_amdgcn_mov_dpp(__float_as_int(v.x), 0x4E, 0xF, 0xF, true));
    r.y = __int_as_float(__builtin_amdgcn_mov_dpp(__float_as_int(v.y), 0x4E, 0xF, 0xF, true));
    return r;
}

__device__ __forceinline__ float waveReduceMax(float v) {
    #pragma unroll
    for (int off = 32; off > 0; off >>= 1) v = fmaxf(v, __shfl_down(v, off, 64));
    return v;
}
__device__ __forceinline__ float waveReduceSum(float v) {
    #pragma unroll
    for (int off = 32; off > 0; off >>= 1) v += __shfl_down(v, off, 64);
    return v;
}

// In-place 16-point DFT: y[k] = sum_n x[n] * w16^(SGN*k*n), natural order in/out.
// Radix-4 x radix-4, all twiddles compile-time constants.
template<int SGN>
__device__ __forceinline__ void dft16(float2 v[16]){
    float2 w[16];
    #pragma unroll
    for (int n0 = 0; n0 < 4; ++n0){
        float2 a = v[n0], b = v[n0+4], c = v[n0+8], d = v[n0+12];
        float2 t0 = cadd(a,c), t1 = csub(a,c), t2 = cadd(b,d), t3 = csub(b,d);
        float2 j3 = (SGN < 0) ? mul_mi(t3) : mul_i(t3);
        w[n0]    = cadd(t0,t2);
        w[4+n0]  = cadd(t1,j3);
        w[8+n0]  = csub(t0,t2);
        w[12+n0] = csub(t1,j3);
    }
    const float C1 = 0.923879532511286756f;  // cos(pi/8)
    const float S1 = 0.382683432365089772f;  // sin(pi/8)
    const float R2 = 0.707106781186547524f;
    const float G = (SGN < 0) ? -1.0f : 1.0f;
    // w[k0*4+n0] *= w16^(SGN*k0*n0); w16^m = (cos(m*pi/8), sin(m*pi/8))
    w[5]  = cmul(w[5],  make_float2( C1,  G*S1));   // m=1
    w[6]  = cmul(w[6],  make_float2( R2,  G*R2));   // m=2
    w[7]  = cmul(w[7],  make_float2( S1,  G*C1));   // m=3
    w[9]  = cmul(w[9],  make_float2( R2,  G*R2));   // m=2
    w[10] = (SGN<0) ? mul_mi(w[10]) : mul_i(w[10]); // m=4
    w[11] = cmul(w[11], make_float2(-R2,  G*R2));   // m=6
    w[13] = cmul(w[13], make_float2( S1,  G*C1));   // m=3
    w[14] = cmul(w[14], make_float2(-R2,  G*R2));   // m=6
    w[15] = cmul(w[15], make_float2(-C1, -G*S1));   // m=9
    #pragma unroll
    for (int k0 = 0; k0 < 4; ++k0){
        float2 a = w[k0*4+0], b = w[k0*4+1], c = w[k0*4+2], d = w[k0*4+3];
        float2 t0 = cadd(a,c), t1 = csub(a,c), t2 = cadd(b,d), t3 = csub(b,d);
        float2 j3 = (SGN < 0) ? mul_mi(t3) : mul_i(t3);
        v[k0]    = cadd(t0,t2);
        v[k0+4]  = cadd(t1,j3);
        v[k0+8]  = csub(t0,t2);
        v[k0+12] = csub(t1,j3);
    }
}

// v[s] *= exp(SGN*i*s*theta), s=0..15. Two sincos anchors keep error ~4 ulp.
template<int SGN>
__device__ __forceinline__ void twchain16(float2 v[16], float theta){
    float th = (SGN < 0) ? -theta : theta;
    float s1,c1; __sincosf(th, &s1, &c1);
    float s4,c4; __sincosf(4.0f*th, &s4, &c4);
    float2 w1 = make_float2(c1,s1), w4 = make_float2(c4,s4);
    float2 lo1 = w1, lo2 = cmul(w1,w1), lo3 = cmul(lo2,w1);
    float2 hi1 = w4, hi2 = cmul(w4,w4), hi3 = cmul(hi2,w4);
    float2 lo[4] = {make_float2(1.f,0.f), lo1, lo2, lo3};
    float2 hi[4] = {make_float2(1.f,0.f), hi1, hi2, hi3};
    #pragma unroll
    for (int s = 1; s < 16; ++s){
        v[s] = cmul(v[s], cmul(hi[s>>2], lo[s&3]));
    }
}

// Forward: x (time, natural) -> spec (fixed scrambled layout).
// N = 16384 = 16(A: over t, n=t*1024+j) x 16(B) x [16 x 4-lane DPP](C).
__global__ __launch_bounds__(THREADS) void fwd_fft_kernel(const float* __restrict__ x,
                                                          float2* __restrict__ spec) {
    __shared__ float2 X[FFT_N];  // 128 KiB
    const int m = blockIdx.x, tid = threadIdx.x;
    float2 v[16];

    // Stage A: thread j=tid; in(t) = exp(i*2pi*x[t*1024+j]), t<8 (zero-pad above)
    #pragma unroll
    for (int t = 0; t < 8; ++t){
        float ph = TWOPI_F * x[m*NLEN + t*1024 + tid];
        float s,c; __sincosf(ph,&s,&c);
        v[t] = make_float2(c,s);
    }
    #pragma unroll
    for (int t = 8; t < 16; ++t) v[t] = make_float2(0.f,0.f);
    dft16<-1>(v);
    twchain16<-1>(v, TWOPI_F * (float)tid / 16384.0f);
    {
        const int baseA = (tid & ~63) + (((tid & 63) + ((tid >> 6) & 15)) & 63);
        #pragma unroll
        for (int s = 0; s < 16; ++s) X[s*1024 + baseA] = v[s];
    }
    __syncthreads();

    // Stage B: s=tid>>6, j'=tid&63; read/write same per-thread set (no barrier inside)
    {
        const int sB = tid >> 6, jB = tid & 63;
        #pragma unroll
        for (int t = 0; t < 16; ++t) v[t] = X[sB*1024 + t*64 + ((jB + t) & 63)];
        dft16<-1>(v);
        twchain16<-1>(v, TWOPI_F * (float)jB / 1024.0f);
        #pragma unroll
        for (int sp = 0; sp < 16; ++sp) X[sB*1024 + sp*64 + ((jB + sp) & 63)] = v[sp];
    }
    __syncthreads();

    // Stage C: blk=tid>>2, j''=tid&3: DFT16 over t, tw W64, DFT4 across 4 lanes (DPP)
    {
        const int blk = tid >> 2, jC = tid & 3;
        const int rot = blk & 15;
        #pragma unroll
        for (int t = 0; t < 16; ++t) v[t] = X[blk*64 + ((t*4 + jC + rot) & 63)];
        dft16<-1>(v);
        twchain16<-1>(v, TWOPI_F * (float)jC / 64.0f);
        const bool odd1 = (jC & 1) != 0;
        const bool odd2 = (jC & 2) != 0;
        #pragma unroll
        for (int e = 0; e < 16; ++e){
            float2 p = dpp_xor2(v[e]);
            float2 t = odd2 ? csub(p, v[e]) : cadd(v[e], p);
            float2 q = dpp_xor1(t);
            float2 re = odd1 ? csub(q, t) : cadd(t, q);                 // l0:y0, l1:y2
            float2 ro = odd1 ? cadd(q, mul_i(t)) : cadd(t, mul_mi(q));  // l2:y1, l3:y3
            v[e] = odd2 ? ro : re;
        }
        const int u = ((jC & 1) << 1) | (jC >> 1);  // lane -> output digit (involution)
        float4* dst = (float4*)(spec + (size_t)m*FFT_N + blk*64 + u*16);
        #pragma unroll
        for (int e = 0; e < 8; ++e)
            dst[e] = make_float4(v[2*e].x, v[2*e].y, v[2*e+1].x, v[2*e+1].y);
    }
}

// Pair kernel: P = spec_b * conj(spec_a) pointwise, then exact adjoint network
// (= unnormalized inverse). Thread j ends holding lags n = t*1024 + j, t in [0,16).
__global__ __launch_bounds__(THREADS) void pair_kernel(const float2* __restrict__ spec,
                                                       float4* __restrict__ rec) {
    __shared__ float2 X[FFT_N];  // 128 KiB
    const int r = blockIdx.x, tid = threadIdx.x;
    int a, b;
    if (r < M_WAVE){ a = r; b = r; }
    else {
        int t = r - M_WAVE; a = 0; int rem = M_WAVE - 1;
        while (t >= rem){ t -= rem; ++a; rem = M_WAVE - 1 - a; }
        b = a + 1 + t;
    }
    const bool is_auto = (r < M_WAVE);
    const int blk = tid >> 2, jC = tid & 3;
    const int u = ((jC & 1) << 1) | (jC >> 1);
    float2 v[16];

    // Load both spectra (coalesced float4), product
    {
        const float4* pa = (const float4*)(spec + (size_t)a*FFT_N + blk*64 + u*16);
        const float4* pb = (const float4*)(spec + (size_t)b*FFT_N + blk*64 + u*16);
        #pragma unroll
        for (int e = 0; e < 8; ++e){
            float4 A = pa[e], B = pb[e];
            v[2*e]   = make_float2(B.x*A.x + B.y*A.y, B.y*A.x - B.x*A.y);
            v[2*e+1] = make_float2(B.z*A.z + B.w*A.w, B.w*A.z - B.z*A.w);
        }
    }
    // Stage C': adjoint lane-DFT4, conj twiddle W64, DFT16^H, LDS write
    {
        const bool odd1 = (jC & 1) != 0;
        const bool odd2 = (jC & 2) != 0;
        #pragma unroll
        for (int e = 0; e < 16; ++e){
            float2 q = dpp_xor1(v[e]);
            float2 t = odd1 ? csub(q, v[e]) : cadd(v[e], q);
            float2 p = dpp_xor2(t);
            float2 re = odd2 ? csub(p, t) : cadd(t, p);                 // l0:out0, l2:out2
            float2 ro = odd2 ? csub(p, mul_i(t)) : cadd(t, mul_i(p));   // l1:out1, l3:out3
            v[e] = odd1 ? ro : re;
        }
        twchain16<+1>(v, TWOPI_F * (float)jC / 64.0f);
        dft16<+1>(v);
        const int rot = blk & 15;
        #pragma unroll
        for (int t = 0; t < 16; ++t) X[blk*64 + ((t*4 + jC + rot) & 63)] = v[t];
    }
    __syncthreads();
    // Stage B'
    {
        const int sB = tid >> 6, jB = tid & 63;
        #pragma unroll
        for (int sp = 0; sp < 16; ++sp) v[sp] = X[sB*1024 + sp*64 + ((jB + sp) & 63)];
        twchain16<+1>(v, TWOPI_F * (float)jB / 1024.0f);
        dft16<+1>(v);
        #pragma unroll
        for (int t = 0; t < 16; ++t) X[sB*1024 + t*64 + ((jB + t) & 63)] = v[t];
    }
    __syncthreads();
    // Stage A': v[t] = 16384 * sigma[t*1024 + tid]
    {
        const int baseA = (tid & ~63) + (((tid & 63) + ((tid >> 6) & 15)) & 63);
        #pragma unroll
        for (int s = 0; s < 16; ++s) v[s] = X[s*1024 + baseA];
        twchain16<+1>(v, TWOPI_F * (float)tid / 16384.0f);
        dft16<+1>(v);
    }

    // Stats. Lags: auto uses n in [N+1, 2N-1]; cross uses all n except N, n=0 double.
    const float CSCALE = 0.1f / (16384.0f * 16384.0f);
    const bool j0 = (tid == 0);
    float uval[16];
    float lm = 0.f, lsum = 0.f;
    #pragma unroll
    for (int t = 0; t < 16; ++t){
        float uu = CSCALE * (v[t].x*v[t].x + v[t].y*v[t].y);
        uval[t] = uu;
        if (is_auto){
            bool valid = (t > 8) || ((t == 8) && !j0);
            if (valid){ lm = fmaxf(lm, uu); lsum += uu; }
        } else {
            bool inv = (t == 8) && j0;
            if (!inv){ lm = fmaxf(lm, uu); lsum += uu; }
            if (t == 0 && j0) lsum += uu;
        }
    }
    __syncthreads();  // X reads done; reuse as scratch

    float* scratch = (float*)X;
    const int lane = tid & 63, wv = tid >> 6;
    float wm = waveReduceMax(lm);
    float wsm = waveReduceSum(lsum);
    if (lane == 0){ scratch[wv] = wm; scratch[16+wv] = wsm; }
    __syncthreads();
    float m_b = scratch[0], sumu = scratch[16];
    #pragma unroll
    for (int i = 1; i < 16; ++i){ m_b = fmaxf(m_b, scratch[i]); sumu += scratch[16+i]; }

    const float invTN2 = 1.0f / 67108.864f;   // 1/(T*N*N)
    float le = 0.f;
    #pragma unroll
    for (int t = 0; t < 16; ++t){
        float ex = __expf((uval[t] - m_b) * invTN2);
        if (is_auto){
            bool valid = (t > 8) || ((t == 8) && !j0);
            if (valid) le += ex;
        } else {
            bool inv = (t == 8) && j0;
            if (!inv) le += ((t == 0 && j0) ? 2.f : 1.f) * ex;
        }
    }
    float wle = waveReduceSum(le);
    if (lane == 0) scratch[32+wv] = wle;
    __syncthreads();
    if (tid == 0){
        float sb2 = 0.f;
        #pragma unroll
        for (int i = 0; i < 16; ++i) sb2 += scratch[32+i];
        rec[r] = make_float4(m_b, sumu, sb2, 0.f);
    }
}

// Merge 528 records -> 7 outputs.
__global__ __launch_bounds__(256) void final_kernel(const float4* __restrict__ rec,
                                                    float* __restrict__ out) {
    __shared__ float smA[256], smC[256];
    __shared__ double sS[256], sA[256], sC[256];
    const int tid = threadIdx.x;

    float mA = 0.f, mC = 0.f;
    for (int r = tid; r < NPAIR; r += 256){
        float mx = rec[r].x;
        if (r < M_WAVE) mA = fmaxf(mA, mx); else mC = fmaxf(mC, mx);
    }
    smA[tid] = mA; smC[tid] = mC;
    __syncthreads();
    for (int s = 128; s > 0; s >>= 1){
        if (tid < s){ smA[tid]=fmaxf(smA[tid],smA[tid+s]); smC[tid]=fmaxf(smC[tid],smC[tid+s]); }
        __syncthreads();
    }
    const float maxA_g = smA[0], maxC_g = smC[0];
    const float Mall = fmaxf(maxA_g, maxC_g);

    const double invTN2 = 1.0/67108.864;
    double S = 0.0, sumA = 0.0, sumC = 0.0;
    for (int r = tid; r < NPAIR; r += 256){
        float4 rv = rec[r];
        S += (double)rv.z * exp(((double)rv.x - (double)Mall)*invTN2);
        if (r < M_WAVE) sumA += (double)rv.y; else sumC += (double)rv.y;
    }
    sS[tid]=S; sA[tid]=sumA; sC[tid]=sumC;
    __syncthreads();
    for (int s = 128; s > 0; s >>= 1){
        if (tid < s){ sS[tid]+=sS[tid+s]; sA[tid]+=sA[tid+s]; sC[tid]+=sC[tid+s]; }
        __syncthreads();
    }
    if (tid == 0){
        const double invN2 = 1.0/67108864.0;
        out[0] = (float)((double)Mall*invN2 + 1e-3*log(sS[0]));
        out[1] = (float)((double)Mall*invN2);
        out[2] = maxA_g;
        out[3] = maxC_g;
        out[4] = (float)((sA[0]+sC[0])*invN2);
        out[5] = (float)sA[0];
        out[6] = (float)sC[0];
    }
}

extern "C" void kernel_launch(void* const* d_in, const int* in_sizes, int n_in,
                              void* d_out, int out_size, void* d_ws, size_t ws_size,
                              hipStream_t stream) {
    (void)in_sizes; (void)n_in; (void)out_size; (void)ws_size;
    const float* x = (const float*)d_in[0];
    float* out = (float*)d_out;

    float2* spec = (float2*)d_ws;
    float4* rec = (float4*)((char*)d_ws + (size_t)M_WAVE * FFT_N * sizeof(float2));

    fwd_fft_kernel<<<M_WAVE, THREADS, 0, stream>>>(x, spec);
    pair_kernel<<<NPAIR, THREADS, 0, stream>>>(spec, rec);
    final_kernel<<<1, 256, 0, stream>>>(rec, out);
}